// Round 2
// baseline (389.068 us; speedup 1.0000x reference)
//
#include <hip/hip_runtime.h>
#include <stdint.h>

// B=8192, E=16, C=256, K=2, H=64, OUT=387
// Reassociation: h = relu(const_h + brelu + lap @ (x_b @ W1)), out = h @ fc_w^T + fc_b
//   const_h[hh] = sum_c cheb_w[2c][hh]   (t0 == ones)
//   W1[c][hh]   = cheb_w[2c+1][hh]
// One wave per batch. Round-2 changes (latency-bound fix):
//   * __launch_bounds__(256,4): allow ~128 VGPRs so loads can be hoisted
//   * phase B': preload ALL 16 x f32x4 up-front (one vmcnt wait, not 8)
//   * phase D: fully unrolled; acc initialized from padded fc_b (no epilogue add)
//   * prep: colsum parallelized over 256 threads (was 256-long serial chain)

typedef __attribute__((ext_vector_type(4))) float f32x4;
typedef __attribute__((ext_vector_type(8))) short s16x8;
typedef __attribute__((ext_vector_type(4))) short s16x4;

// workspace byte offsets
#define WS_CH_B    0       // 64 f32: colsum(even cheb rows) + brelu_bias
#define WS_LAP_B   256     // 256 f32: fp32 laplacian (fallback path)
#define WS_LAPA_B  1280    // 64*4 bf16: lap packed as 16x16x16 A-fragments
#define WS_FCB_B   1792    // 400 f32: fc_b zero-padded
#define WS_W1T_B   4096    // [64][256] bf16: W1T[hh][c] = cheb_w[2c+1][hh]
#define WS_FCW_B   36864   // [400][64] bf16: fc_w rows, zero-padded to 400
#define FCW_ROWS   400

static __device__ __forceinline__ short f2bf(float f) {
    union { float f; uint32_t u; } v; v.f = f;
    uint32_t r = (v.u + 0x7fffu + ((v.u >> 16) & 1u)) >> 16;  // RNE
    return (short)r;
}

__global__ void prep_kernel(const float* __restrict__ adj,
                            const float* __restrict__ adj_bias,
                            const float* __restrict__ cheb_w,
                            const float* __restrict__ brelu_bias,
                            const float* __restrict__ fc_w,
                            const float* __restrict__ fc_b,
                            char* __restrict__ ws) {
    float* chf  = (float*)(ws + WS_CH_B);
    float* lapf = (float*)(ws + WS_LAP_B);
    short* lapA = (short*)(ws + WS_LAPA_B);
    float* fcbp = (float*)(ws + WS_FCB_B);
    short* w1t  = (short*)(ws + WS_W1T_B);
    short* fcw  = (short*)(ws + WS_FCW_B);
    int t = threadIdx.x;

    if (blockIdx.x == 0) {
        __shared__ float sw[16][17];
        __shared__ float sdre[16];
        __shared__ float slap[16][16];
        __shared__ float csum[4][64];
        float ab = adj_bias[0];
        {
            int i = t >> 4, j = t & 15;
            sw[i][j] = fmaxf(adj[t] + ab, 0.f);
        }
        {   // colsum of even cheb rows: 4 partials x 64 h, parallel over 256 threads
            int hh = t & 63, part = t >> 6;
            float s = 0.f;
            #pragma unroll 8
            for (int i = 0; i < 64; ++i) s += cheb_w[(2 * (part * 64 + i)) * 64 + hh];
            csum[part][hh] = s;
        }
        __syncthreads();
        if (t < 16) {
            float s = 0.f;
            #pragma unroll
            for (int j = 0; j < 16; ++j) s += sw[t][j];
            sdre[t] = 1.0f / sqrtf(s + 1e-5f);
        }
        __syncthreads();
        {
            int i = t >> 4, j = t & 15;
            float l = (i == j ? 1.f : 0.f) - sdre[i] * sw[i][j] * sdre[j];
            slap[i][j] = l;
            lapf[t] = l;
        }
        __syncthreads();
        if (t < 64) {
            int m = t & 15, qq = t >> 4;
            #pragma unroll
            for (int i = 0; i < 4; ++i)
                lapA[t * 4 + i] = f2bf(slap[m][qq * 4 + i]);  // A[m][k=qq*4+i]
            chf[t] = csum[0][t] + csum[1][t] + csum[2][t] + csum[3][t] + brelu_bias[t];
        }
        for (int o = t; o < 400; o += 256) fcbp[o] = (o < 387) ? fc_b[o] : 0.f;
    }
    int gt = blockIdx.x * blockDim.x + t;
    int nthr = gridDim.x * blockDim.x;
    for (int idx = gt; idx < 64 * 256; idx += nthr) {
        int hh = idx >> 8, c = idx & 255;
        w1t[idx] = f2bf(cheb_w[(2 * c + 1) * 64 + hh]);
    }
    for (int idx = gt; idx < FCW_ROWS * 64; idx += nthr) {
        fcw[idx] = (idx < 387 * 64) ? f2bf(fc_w[idx]) : (short)0;
    }
}

__global__ __launch_bounds__(256, 4) void fused_kernel(
        const float* __restrict__ x,
        const char* __restrict__ ws,
        float* __restrict__ out) {
    const float* chf  = (const float*)(ws + WS_CH_B);
    const short* lapA = (const short*)(ws + WS_LAPA_B);
    const float* fcbp = (const float*)(ws + WS_FCB_B);
    const short* w1t  = (const short*)(ws + WS_W1T_B);
    const short* fcw  = (const short*)(ws + WS_FCW_B);

    __shared__ __align__(16) short hs[4][16][72];  // bf16 h per wave, +8 pad

    const int lane = threadIdx.x & 63;
    const int wave = threadIdx.x >> 6;
    const int n = lane & 15;   // MFMA col (B/C) == A row m
    const int q = lane >> 4;   // quad
    const long b = (long)blockIdx.x * 4 + wave;   // one batch per wave

    const float* xb = x + b * 4096;

    // ---- Phase B': g = bf16(x_b) @ W1   (M=16 rows, N=64 hh, K=256 c)
    // Preload ALL x for this wave's fragments: 16 independent 16B loads in flight.
    const float* xrow = xb + n * 256 + q * 8;
    f32x4 xr[16];
    #pragma unroll
    for (int kb = 0; kb < 8; ++kb) {
        xr[2 * kb]     = *(const f32x4*)(xrow + kb * 32);
        xr[2 * kb + 1] = *(const f32x4*)(xrow + kb * 32 + 4);
    }
    s16x8 af[8];
    #pragma unroll
    for (int kb = 0; kb < 8; ++kb) {
        f32x4 xa = xr[2 * kb], xc = xr[2 * kb + 1];
        af[kb][0] = f2bf(xa[0]); af[kb][1] = f2bf(xa[1]);
        af[kb][2] = f2bf(xa[2]); af[kb][3] = f2bf(xa[3]);
        af[kb][4] = f2bf(xc[0]); af[kb][5] = f2bf(xc[1]);
        af[kb][6] = f2bf(xc[2]); af[kb][7] = f2bf(xc[3]);
    }
    f32x4 g[4];
    #pragma unroll
    for (int nt = 0; nt < 4; ++nt) g[nt] = (f32x4){0.f, 0.f, 0.f, 0.f};
    #pragma unroll
    for (int kb = 0; kb < 8; ++kb) {
        const int k0 = kb * 32 + q * 8;
        #pragma unroll
        for (int nt = 0; nt < 4; ++nt) {
            s16x8 bf = *(const s16x8*)(w1t + (nt * 16 + n) * 256 + k0);
            g[nt] = __builtin_amdgcn_mfma_f32_16x16x32_bf16(af[kb], bf, g[nt], 0, 0, 0);
        }
    }

    // ---- Phase C': h = lap @ g  (K=16). g's C-layout == 16x16x16 B-layout.
    f32x4 h[4];
#if defined(__has_builtin) && __has_builtin(__builtin_amdgcn_mfma_f32_16x16x16bf16_1k)
    {
        s16x4 la = *(const s16x4*)(lapA + lane * 4);
        const f32x4 z4 = (f32x4){0.f, 0.f, 0.f, 0.f};
        #pragma unroll
        for (int nt = 0; nt < 4; ++nt) {
            s16x4 gb;
            gb[0] = f2bf(g[nt][0]); gb[1] = f2bf(g[nt][1]);
            gb[2] = f2bf(g[nt][2]); gb[3] = f2bf(g[nt][3]);
            h[nt] = __builtin_amdgcn_mfma_f32_16x16x16bf16_1k(la, gb, z4, 0, 0, 0);
        }
    }
#else
    {
        __shared__ float gs[4][16][68];
        const float* lapf = (const float*)(ws + WS_LAP_B);
        #pragma unroll
        for (int r = 0; r < 4; ++r) {
            gs[wave][q * 4 + r][0 * 16 + n] = g[0][r];
            gs[wave][q * 4 + r][1 * 16 + n] = g[1][r];
            gs[wave][q * 4 + r][2 * 16 + n] = g[2][r];
            gs[wave][q * 4 + r][3 * 16 + n] = g[3][r];
        }
        __syncthreads();
        #pragma unroll
        for (int nt = 0; nt < 4; ++nt) h[nt] = (f32x4){0.f, 0.f, 0.f, 0.f};
        #pragma unroll
        for (int e = 0; e < 16; ++e) {
            float l0 = lapf[(q * 4 + 0) * 16 + e];
            float l1 = lapf[(q * 4 + 1) * 16 + e];
            float l2 = lapf[(q * 4 + 2) * 16 + e];
            float l3 = lapf[(q * 4 + 3) * 16 + e];
            #pragma unroll
            for (int nt = 0; nt < 4; ++nt) {
                float gv = gs[wave][e][nt * 16 + n];
                h[nt][0] += l0 * gv; h[nt][1] += l1 * gv;
                h[nt][2] += l2 * gv; h[nt][3] += l3 * gv;
            }
        }
    }
#endif

    // ---- relu(+const) epilogue -> bf16 -> LDS (A-operand layout for phase D)
    #pragma unroll
    for (int nt = 0; nt < 4; ++nt) {
        float cv = chf[nt * 16 + n];
        #pragma unroll
        for (int r = 0; r < 4; ++r) {
            float v = fmaxf(h[nt][r] + cv, 0.f);
            hs[wave][q * 4 + r][nt * 16 + n] = f2bf(v);
        }
    }
    __syncthreads();  // deps are wave-internal, but cheap and safe

    // ---- Phase D': out = h @ fc_w^T  (M=16 e, N=387 o, K=64 hh)
    s16x8 ha0 = *(const s16x8*)(&hs[wave][n][q * 8]);
    s16x8 ha1 = *(const s16x8*)(&hs[wave][n][32 + q * 8]);
    float* outb = out + (b * 16 + q * 4) * 387;
    #pragma unroll
    for (int tt = 0; tt < 25; ++tt) {
        const int o0 = tt * 16;
        s16x8 fb0 = *(const s16x8*)(fcw + (o0 + n) * 64 + q * 8);
        s16x8 fb1 = *(const s16x8*)(fcw + (o0 + n) * 64 + 32 + q * 8);
        const int o = o0 + n;
        float bias = fcbp[o];
        f32x4 acc = (f32x4){bias, bias, bias, bias};
        acc = __builtin_amdgcn_mfma_f32_16x16x32_bf16(ha0, fb0, acc, 0, 0, 0);
        acc = __builtin_amdgcn_mfma_f32_16x16x32_bf16(ha1, fb1, acc, 0, 0, 0);
        if (o < 387) {
            outb[0 * 387 + o] = acc[0];
            outb[1 * 387 + o] = acc[1];
            outb[2 * 387 + o] = acc[2];
            outb[3 * 387 + o] = acc[3];
        }
    }
}

extern "C" void kernel_launch(void* const* d_in, const int* in_sizes, int n_in,
                              void* d_out, int out_size, void* d_ws, size_t ws_size,
                              hipStream_t stream) {
    const float* x          = (const float*)d_in[0];
    const float* adj        = (const float*)d_in[1];
    const float* adj_bias   = (const float*)d_in[2];
    const float* cheb_w     = (const float*)d_in[3];
    const float* brelu_bias = (const float*)d_in[4];
    const float* fc_w       = (const float*)d_in[5];
    const float* fc_b       = (const float*)d_in[6];
    float* outp = (float*)d_out;
    char* ws = (char*)d_ws;

    prep_kernel<<<64, 256, 0, stream>>>(adj, adj_bias, cheb_w, brelu_bias, fc_w, fc_b, ws);
    fused_kernel<<<2048, 256, 0, stream>>>(x, ws, outp);
}

// Round 3
// 345.604 us; speedup vs baseline: 1.1258x; 1.1258x over previous
//
#include <hip/hip_runtime.h>
#include <stdint.h>

// B=8192, E=16, C=256, K=2, H=64, OUT=387
// h = relu(const_h + brelu + lap @ (x_b @ W1)), out = h @ fc_w^T + fc_b
// Round-3: B-operands (W1, fc_w) pre-swizzled into MFMA fragment order so every
// hot-loop load is lane-contiguous 1KB; explicit 1-ahead software pipelines in
// phase B' and phase D; no __syncthreads before phase D (lgkmcnt wait only).

typedef __attribute__((ext_vector_type(4))) float f32x4;
typedef __attribute__((ext_vector_type(8))) short s16x8;
typedef __attribute__((ext_vector_type(4))) short s16x4;

// workspace byte offsets
#define WS_CH_B    0       // 64 f32: colsum(even cheb rows) + brelu_bias
#define WS_LAP_B   256     // 256 f32: fp32 laplacian (fallback path)
#define WS_LAPA_B  1280    // 64*4 bf16: lap as 16x16x16 A-fragments
#define WS_FCB_B   1792    // 400 f32: fc_b zero-padded
#define WS_W1T2_B  4096    // 32 frags * 512 shorts: W1 B-frags, frag=(kb*4+nt)
#define WS_FCW2_B  36864   // 50 frags * 512 shorts: fc_w B-frags, frag=(tt*2+f)

static __device__ __forceinline__ short f2bf(float f) {
    union { float f; uint32_t u; } v; v.f = f;
    uint32_t r = (v.u + 0x7fffu + ((v.u >> 16) & 1u)) >> 16;  // RNE
    return (short)r;
}

__global__ void prep_kernel(const float* __restrict__ adj,
                            const float* __restrict__ adj_bias,
                            const float* __restrict__ cheb_w,
                            const float* __restrict__ brelu_bias,
                            const float* __restrict__ fc_w,
                            const float* __restrict__ fc_b,
                            char* __restrict__ ws) {
    float* chf  = (float*)(ws + WS_CH_B);
    float* lapf = (float*)(ws + WS_LAP_B);
    short* lapA = (short*)(ws + WS_LAPA_B);
    float* fcbp = (float*)(ws + WS_FCB_B);
    short* w1t2 = (short*)(ws + WS_W1T2_B);
    short* fcw2 = (short*)(ws + WS_FCW2_B);
    int t = threadIdx.x;

    if (blockIdx.x == 0) {
        __shared__ float sw[16][17];
        __shared__ float sdre[16];
        __shared__ float slap[16][16];
        __shared__ float csum[4][64];
        float ab = adj_bias[0];
        {
            int i = t >> 4, j = t & 15;
            sw[i][j] = fmaxf(adj[t] + ab, 0.f);
        }
        {   // colsum of even cheb rows, parallel over 256 threads
            int hh = t & 63, part = t >> 6;
            float s = 0.f;
            #pragma unroll 8
            for (int i = 0; i < 64; ++i) s += cheb_w[(2 * (part * 64 + i)) * 64 + hh];
            csum[part][hh] = s;
        }
        __syncthreads();
        if (t < 16) {
            float s = 0.f;
            #pragma unroll
            for (int j = 0; j < 16; ++j) s += sw[t][j];
            sdre[t] = 1.0f / sqrtf(s + 1e-5f);
        }
        __syncthreads();
        {
            int i = t >> 4, j = t & 15;
            float l = (i == j ? 1.f : 0.f) - sdre[i] * sw[i][j] * sdre[j];
            slap[i][j] = l;
            lapf[t] = l;
        }
        __syncthreads();
        if (t < 64) {
            int m = t & 15, qq = t >> 4;
            #pragma unroll
            for (int i = 0; i < 4; ++i)
                lapA[t * 4 + i] = f2bf(slap[m][qq * 4 + i]);  // A[m][k=qq*4+i]
            chf[t] = csum[0][t] + csum[1][t] + csum[2][t] + csum[3][t] + brelu_bias[t];
        }
        for (int o = t; o < 400; o += 256) fcbp[o] = (o < 387) ? fc_b[o] : 0.f;
    }
    int gt = blockIdx.x * blockDim.x + t;
    int nthr = gridDim.x * blockDim.x;
    // W1 B-fragments: frag=(kb*4+nt), element = frag*512 + lane*8 + j
    //   B[k = kb*32 + (lane>>4)*8 + j][col = nt*16 + (lane&15)], W1[c][h]=cheb_w[2c+1][h]
    for (int idx = gt; idx < 32 * 512; idx += nthr) {
        int frag = idx >> 9, r = idx & 511;
        int lane = r >> 3, j = r & 7;
        int kb = frag >> 2, nt = frag & 3;
        int k = kb * 32 + (lane >> 4) * 8 + j;
        int col = nt * 16 + (lane & 15);
        w1t2[idx] = f2bf(cheb_w[(2 * k + 1) * 64 + col]);
    }
    // fc_w B-fragments: frag=(tt*2+f), element = frag*512 + lane*8 + j
    //   B[k = f*32 + (lane>>4)*8 + j][o = tt*16 + (lane&15)], fc_w[o][k]
    for (int idx = gt; idx < 50 * 512; idx += nthr) {
        int frag = idx >> 9, r = idx & 511;
        int lane = r >> 3, j = r & 7;
        int tt = frag >> 1, f = frag & 1;
        int o = tt * 16 + (lane & 15);
        int k = f * 32 + (lane >> 4) * 8 + j;
        fcw2[idx] = (o < 387) ? f2bf(fc_w[o * 64 + k]) : (short)0;
    }
}

__global__ __launch_bounds__(256) void fused_kernel(
        const float* __restrict__ x,
        const char* __restrict__ ws,
        float* __restrict__ out) {
    const float* chf  = (const float*)(ws + WS_CH_B);
    const short* lapA = (const short*)(ws + WS_LAPA_B);
    const float* fcbp = (const float*)(ws + WS_FCB_B);
    const short* w1t2 = (const short*)(ws + WS_W1T2_B);
    const short* fcw2 = (const short*)(ws + WS_FCW2_B);

    __shared__ __align__(16) short hs[4][16][72];  // bf16 h per wave, +8 pad

    const int lane = threadIdx.x & 63;
    const int wave = threadIdx.x >> 6;
    const int n = lane & 15;   // MFMA col (B/C) == A row m
    const int q = lane >> 4;   // quad
    const long b = (long)blockIdx.x * 4 + wave;   // one batch per wave

    // ---- Phase B': g = bf16(x_b) @ W1   (M=16 rows, N=64 hh, K=256 c)
    const float* xrow = x + b * 4096 + n * 256 + q * 8;
    f32x4 xr[16];
    #pragma unroll
    for (int kb = 0; kb < 8; ++kb) {
        xr[2 * kb]     = *(const f32x4*)(xrow + kb * 32);
        xr[2 * kb + 1] = *(const f32x4*)(xrow + kb * 32 + 4);
    }
    s16x8 af[8];
    #pragma unroll
    for (int kb = 0; kb < 8; ++kb) {
        f32x4 xa = xr[2 * kb], xc = xr[2 * kb + 1];
        af[kb][0] = f2bf(xa[0]); af[kb][1] = f2bf(xa[1]);
        af[kb][2] = f2bf(xa[2]); af[kb][3] = f2bf(xa[3]);
        af[kb][4] = f2bf(xc[0]); af[kb][5] = f2bf(xc[1]);
        af[kb][6] = f2bf(xc[2]); af[kb][7] = f2bf(xc[3]);
    }
    // dense fragment loads, 1-ahead pipeline
    const short* w1 = w1t2 + lane * 8;
    s16x8 bfr[2][4];
    #pragma unroll
    for (int nt = 0; nt < 4; ++nt)
        bfr[0][nt] = *(const s16x8*)(w1 + nt * 512);
    f32x4 g[4];
    #pragma unroll
    for (int nt = 0; nt < 4; ++nt) g[nt] = (f32x4){0.f, 0.f, 0.f, 0.f};
    #pragma unroll
    for (int kb = 0; kb < 8; ++kb) {
        const int cur = kb & 1;
        if (kb < 7) {
            #pragma unroll
            for (int nt = 0; nt < 4; ++nt)
                bfr[cur ^ 1][nt] = *(const s16x8*)(w1 + ((kb + 1) * 4 + nt) * 512);
        }
        #pragma unroll
        for (int nt = 0; nt < 4; ++nt)
            g[nt] = __builtin_amdgcn_mfma_f32_16x16x32_bf16(af[kb], bfr[cur][nt], g[nt], 0, 0, 0);
    }

    // ---- Phase C': h = lap @ g  (K=16). g's C-layout == 16x16x16 B-layout.
    f32x4 h[4];
#if defined(__has_builtin) && __has_builtin(__builtin_amdgcn_mfma_f32_16x16x16bf16_1k)
    {
        s16x4 la = *(const s16x4*)(lapA + lane * 4);
        const f32x4 z4 = (f32x4){0.f, 0.f, 0.f, 0.f};
        #pragma unroll
        for (int nt = 0; nt < 4; ++nt) {
            s16x4 gb;
            gb[0] = f2bf(g[nt][0]); gb[1] = f2bf(g[nt][1]);
            gb[2] = f2bf(g[nt][2]); gb[3] = f2bf(g[nt][3]);
            h[nt] = __builtin_amdgcn_mfma_f32_16x16x16bf16_1k(la, gb, z4, 0, 0, 0);
        }
    }
#else
    {
        __shared__ float gs[4][16][68];
        const float* lapf = (const float*)(ws + WS_LAP_B);
        #pragma unroll
        for (int r = 0; r < 4; ++r) {
            gs[wave][q * 4 + r][0 * 16 + n] = g[0][r];
            gs[wave][q * 4 + r][1 * 16 + n] = g[1][r];
            gs[wave][q * 4 + r][2 * 16 + n] = g[2][r];
            gs[wave][q * 4 + r][3 * 16 + n] = g[3][r];
        }
        __syncthreads();
        #pragma unroll
        for (int nt = 0; nt < 4; ++nt) h[nt] = (f32x4){0.f, 0.f, 0.f, 0.f};
        #pragma unroll
        for (int e = 0; e < 16; ++e) {
            float l0 = lapf[(q * 4 + 0) * 16 + e];
            float l1 = lapf[(q * 4 + 1) * 16 + e];
            float l2 = lapf[(q * 4 + 2) * 16 + e];
            float l3 = lapf[(q * 4 + 3) * 16 + e];
            #pragma unroll
            for (int nt = 0; nt < 4; ++nt) {
                float gv = gs[wave][e][nt * 16 + n];
                h[nt][0] += l0 * gv; h[nt][1] += l1 * gv;
                h[nt][2] += l2 * gv; h[nt][3] += l3 * gv;
            }
        }
    }
#endif

    // ---- relu(+const) epilogue -> bf16 -> LDS (A-operand layout for phase D)
    #pragma unroll
    for (int nt = 0; nt < 4; ++nt) {
        float cv = chf[nt * 16 + n];
        #pragma unroll
        for (int r = 0; r < 4; ++r) {
            float v = fmaxf(h[nt][r] + cv, 0.f);
            hs[wave][q * 4 + r][nt * 16 + n] = f2bf(v);
        }
    }
    // hs is wave-private: only LDS-op ordering needed, NOT a block barrier
    // (__syncthreads would force vmcnt(0), draining the phase-D prefetch).
    __builtin_amdgcn_s_waitcnt(0xC07F);  // lgkmcnt(0), vmcnt/expcnt unconstrained

    // ---- Phase D: out = h @ fc_w^T  (M=16 e, N=387 o, K=64 hh)
    // 25 o-tiles in 5 chunks of 5, 1-ahead prefetch of dense fragments.
    const short* fw = fcw2 + lane * 8;
    s16x8 fb[2][10];
    #pragma unroll
    for (int t = 0; t < 5; ++t) {
        fb[0][2 * t]     = *(const s16x8*)(fw + (t * 2 + 0) * 512);
        fb[0][2 * t + 1] = *(const s16x8*)(fw + (t * 2 + 1) * 512);
    }
    s16x8 ha0 = *(const s16x8*)(&hs[wave][n][q * 8]);
    s16x8 ha1 = *(const s16x8*)(&hs[wave][n][32 + q * 8]);
    float* outb = out + (b * 16 + q * 4) * 387;
    #pragma unroll
    for (int c = 0; c < 5; ++c) {
        if (c < 4) {
            #pragma unroll
            for (int t = 0; t < 5; ++t) {
                int tt = (c + 1) * 5 + t;
                fb[(c + 1) & 1][2 * t]     = *(const s16x8*)(fw + (tt * 2 + 0) * 512);
                fb[(c + 1) & 1][2 * t + 1] = *(const s16x8*)(fw + (tt * 2 + 1) * 512);
            }
        }
        #pragma unroll
        for (int t = 0; t < 5; ++t) {
            const int tt = c * 5 + t;
            const int o = tt * 16 + n;
            float bias = fcbp[o];
            f32x4 acc = (f32x4){bias, bias, bias, bias};
            acc = __builtin_amdgcn_mfma_f32_16x16x32_bf16(ha0, fb[c & 1][2 * t], acc, 0, 0, 0);
            acc = __builtin_amdgcn_mfma_f32_16x16x32_bf16(ha1, fb[c & 1][2 * t + 1], acc, 0, 0, 0);
            if (o < 387) {
                outb[0 * 387 + o] = acc[0];
                outb[1 * 387 + o] = acc[1];
                outb[2 * 387 + o] = acc[2];
                outb[3 * 387 + o] = acc[3];
            }
        }
    }
}

extern "C" void kernel_launch(void* const* d_in, const int* in_sizes, int n_in,
                              void* d_out, int out_size, void* d_ws, size_t ws_size,
                              hipStream_t stream) {
    const float* x          = (const float*)d_in[0];
    const float* adj        = (const float*)d_in[1];
    const float* adj_bias   = (const float*)d_in[2];
    const float* cheb_w     = (const float*)d_in[3];
    const float* brelu_bias = (const float*)d_in[4];
    const float* fc_w       = (const float*)d_in[5];
    const float* fc_b       = (const float*)d_in[6];
    float* outp = (float*)d_out;
    char* ws = (char*)d_ws;

    prep_kernel<<<64, 256, 0, stream>>>(adj, adj_bias, cheb_w, brelu_bias, fc_w, fc_b, ws);
    fused_kernel<<<2048, 256, 0, stream>>>(x, ws, outp);
}